// Round 4
// baseline (161.192 us; speedup 1.0000x reference)
//
#include <hip/hip_runtime.h>
#include <hip/hip_bf16.h>

typedef __bf16 bf16x8 __attribute__((ext_vector_type(8)));
typedef __bf16 bf16x2 __attribute__((ext_vector_type(2)));
typedef float f32x4 __attribute__((ext_vector_type(4)));

#define K2f 2.0813689810056077f   // log2(e)^2
#define LN2f 0.6931471805599453f

typedef __attribute__((address_space(3))) unsigned int lds_u32;
typedef __attribute__((address_space(1))) unsigned int glb_u32;

__device__ __forceinline__ void gload16(const void* g, void* l) {
    __builtin_amdgcn_global_load_lds((const glb_u32*)g, (lds_u32*)l, 16, 0, 0);
}

// Kernel 1: prototypes f32 -> bf16 in MFMA B-fragment order + ysq2 = ||y||^2*log2e^2.
// Element e of class c, dim d (d = kk*32 + lg*8 + e) -> bf16 offset
// ((c>>4)*4 + kk)*64*8 + (lg*16 + (c&15))*8 + e.  Tile ct occupies 4096 B.
__global__ void dce_prep(const float* __restrict__ protos,
                         unsigned short* __restrict__ bpf,
                         float* __restrict__ ysq2) {
    int c = blockIdx.x;
    int lane = threadIdx.x;  // dims 2*lane, 2*lane+1
    float2 f = ((const float2*)(protos))[c * 64 + lane];
    int d0 = lane * 2;
    int kk = d0 >> 5, sub = d0 & 31, lg = sub >> 3, e = sub & 7;
    size_t o = (((size_t)((c >> 4) * 4 + kk) * 64) + lg * 16 + (c & 15)) * 8 + e;
    bf16x2 h;
    h.x = (__bf16)f.x;
    h.y = (__bf16)f.y;
    *(bf16x2*)(bpf + o) = h;
    float xs = f.x * f.x + f.y * f.y;
#pragma unroll
    for (int d = 1; d < 64; d <<= 1) xs += __shfl_xor(xs, d);
    if (lane == 0) ysq2[c] = xs * K2f;
}

// Kernel 2: fused distance-softmax-NLL.
// 2048 blocks x 256 threads; block owns 128 rows, wave owns 32 rows (2 M-frags).
// B tiles staged in LDS (double-buffered, global_load_lds), 1 barrier/tile.
// logits <= 0 -> softmax max pinned at 0:
//   nll = dist_label + ln2 * log2( sum_c 2^(-log2e * dist_c) ).
__global__ __launch_bounds__(256, 4) void dce_main(
    const float* __restrict__ feats,
    const float* __restrict__ protos,
    const unsigned short* __restrict__ bpf,
    const float* __restrict__ ysq2,
    const int* __restrict__ labels,
    float* __restrict__ partials, int C) {
    const int tid = threadIdx.x;
    const int lane = tid & 63;
    const int w = tid >> 6;
    const int row0 = blockIdx.x * 128;
    const int rbase = row0 + w * 32;
    const int lr = lane & 15;
    const int lg = lane >> 4;

    __shared__ __align__(16) unsigned char bsm[2][4096];
    __shared__ float red[4];

    // ---- Phase 1: exact f32 label distance, 2 threads per row ----
    const int r1 = row0 + (tid >> 1);
    const int half = tid & 1;
    const int lab = labels[r1];
    const float4* fx = (const float4*)feats + (size_t)r1 * 32 + half * 16;
    const float4* px = (const float4*)protos + (size_t)lab * 32 + half * 16;
    float xx = 0.f, yy = 0.f, xy = 0.f;
#pragma unroll
    for (int i = 0; i < 16; ++i) {
        float4 f = fx[i], p = px[i];
        xx = fmaf(f.x, f.x, fmaf(f.y, f.y, fmaf(f.z, f.z, fmaf(f.w, f.w, xx))));
        yy = fmaf(p.x, p.x, fmaf(p.y, p.y, fmaf(p.z, p.z, fmaf(p.w, p.w, yy))));
        xy = fmaf(f.x, p.x, fmaf(f.y, p.y, fmaf(f.z, p.z, fmaf(f.w, p.w, xy))));
    }
    xx += __shfl_xor(xx, 1);
    yy += __shfl_xor(yy, 1);
    xy += __shfl_xor(xy, 1);
    const float ld = __builtin_amdgcn_sqrtf(fmaxf(fmaf(-2.f, xy, xx + yy), 0.f));

    // ---- A fragments: 2 M-frags x 4 k-slices ----
    bf16x8 a[2][4];
    const float4* f4 = (const float4*)feats;
#pragma unroll
    for (int m = 0; m < 2; ++m) {
        size_t r = (size_t)(rbase + m * 16 + lr);
#pragma unroll
        for (int kk = 0; kk < 4; ++kk) {
            size_t idx = r * 32 + kk * 8 + lg * 2;
            float4 lo = f4[idx];
            float4 hi = f4[idx + 1];
            bf16x8 v;
            v[0] = (__bf16)lo.x; v[1] = (__bf16)lo.y; v[2] = (__bf16)lo.z; v[3] = (__bf16)lo.w;
            v[4] = (__bf16)hi.x; v[5] = (__bf16)hi.y; v[6] = (__bf16)hi.z; v[7] = (__bf16)hi.w;
            a[m][kk] = v;
        }
    }

    // ||x||^2 (scaled) in C/D layout: element (m,reg) covers row m*16+lg*4+reg,
    // whose exact xx lives at lane 2*(that row-in-wave).
    float xsqs[2][4];
#pragma unroll
    for (int m = 0; m < 2; ++m)
#pragma unroll
        for (int reg = 0; reg < 4; ++reg)
            xsqs[m][reg] = K2f * __shfl(xx, 2 * (m * 16 + lg * 4 + reg));

    float lacc[2][4];
#pragma unroll
    for (int m = 0; m < 2; ++m)
#pragma unroll
        for (int reg = 0; reg < 4; ++reg) lacc[m][reg] = 0.f;

    // ---- Main loop: LDS double-buffered B tiles ----
    const char* bpc = (const char*)bpf;
    const int nt = C >> 4;
    gload16(bpc + (size_t)tid * 16, &bsm[0][tid * 16]);  // stage tile 0
    int p = 0;
    for (int t = 0; t < nt; ++t) {
        __syncthreads();  // implicit vmcnt drain -> bsm[p] ready; prior reads done
        if (t + 1 < nt)
            gload16(bpc + (size_t)(t + 1) * 4096 + tid * 16, &bsm[p ^ 1][tid * 16]);
        const bf16x8* bl = (const bf16x8*)&bsm[p][0];
        bf16x8 b0 = bl[lane];
        bf16x8 b1 = bl[64 + lane];
        bf16x8 b2 = bl[128 + lane];
        bf16x8 b3 = bl[192 + lane];
        const float yq2 = ysq2[t * 16 + lr];
#pragma unroll
        for (int m = 0; m < 2; ++m) {
            f32x4 acc = {0.f, 0.f, 0.f, 0.f};
            acc = __builtin_amdgcn_mfma_f32_16x16x32_bf16(a[m][0], b0, acc, 0, 0, 0);
            acc = __builtin_amdgcn_mfma_f32_16x16x32_bf16(a[m][1], b1, acc, 0, 0, 0);
            acc = __builtin_amdgcn_mfma_f32_16x16x32_bf16(a[m][2], b2, acc, 0, 0, 0);
            acc = __builtin_amdgcn_mfma_f32_16x16x32_bf16(a[m][3], b3, acc, 0, 0, 0);
#pragma unroll
            for (int reg = 0; reg < 4; ++reg) {
                float d = fmaf(-2.f * K2f, acc[reg], xsqs[m][reg] + yq2);
                d = fmaxf(d, 0.f);
                float s = __builtin_amdgcn_sqrtf(d);      // = log2e * dist
                lacc[m][reg] += __builtin_amdgcn_exp2f(-s);
            }
        }
        p ^= 1;
    }

    // ---- Reduce over 16 column-lanes per row, add exact label distance ----
    float ssum = 0.f;
#pragma unroll
    for (int m = 0; m < 2; ++m)
#pragma unroll
        for (int reg = 0; reg < 4; ++reg) {
            float l = lacc[m][reg];
            l += __shfl_xor(l, 1);
            l += __shfl_xor(l, 2);
            l += __shfl_xor(l, 4);
            l += __shfl_xor(l, 8);
            float ldv = __shfl(ld, 2 * (m * 16 + lg * 4 + reg));
            if (lr == 0) ssum += ldv + LN2f * __builtin_amdgcn_logf(l);
        }
    ssum += __shfl_xor(ssum, 16);
    ssum += __shfl_xor(ssum, 32);

    if (lane == 0) red[w] = ssum;
    __syncthreads();
    if (tid == 0) partials[blockIdx.x] = red[0] + red[1] + red[2] + red[3];
}

// Kernel 3: deterministic reduction of per-block partials -> mean.
__global__ void dce_finish(const float* __restrict__ partials,
                           float* __restrict__ out, int nblocks, float invN) {
    int tid = threadIdx.x;  // 256
    float s = 0.f;
    for (int i = tid; i < nblocks; i += 256) s += partials[i];
#pragma unroll
    for (int d = 1; d < 64; d <<= 1) s += __shfl_xor(s, d);
    __shared__ float red[4];
    if ((tid & 63) == 0) red[tid >> 6] = s;
    __syncthreads();
    if (tid == 0) out[0] = (red[0] + red[1] + red[2] + red[3]) * invN;
}

extern "C" void kernel_launch(void* const* d_in, const int* in_sizes, int n_in,
                              void* d_out, int out_size, void* d_ws, size_t ws_size,
                              hipStream_t stream) {
    const float* feats = (const float*)d_in[0];
    const float* protos = (const float*)d_in[1];
    const int* labels = (const int*)d_in[2];
    const int N = in_sizes[2];          // 262144
    const int C = in_sizes[1] / 128;    // 1024
    float* out = (float*)d_out;

    // Workspace: [bpf: C*128*2B][ysq2: C*4B][partials: N/128*4B]
    unsigned short* bpf = (unsigned short*)d_ws;
    float* ysq2 = (float*)((char*)d_ws + (size_t)C * 128 * 2);
    float* partials = ysq2 + C;
    const int nblocks = N / 128;

    dce_prep<<<C, 64, 0, stream>>>(protos, bpf, ysq2);
    dce_main<<<nblocks, 256, 0, stream>>>(feats, protos, bpf, ysq2, labels, partials, C);
    dce_finish<<<1, 256, 0, stream>>>(partials, out, nblocks, 1.0f / (float)N);
}

// Round 5
// 149.878 us; speedup vs baseline: 1.0755x; 1.0755x over previous
//
#include <hip/hip_runtime.h>
#include <hip/hip_bf16.h>

typedef __bf16 bf16x8 __attribute__((ext_vector_type(8)));
typedef __bf16 bf16x2 __attribute__((ext_vector_type(2)));
typedef float f32x4 __attribute__((ext_vector_type(4)));

#define K2f 2.0813689810056077f   // log2(e)^2
#define LN2f 0.6931471805599453f

typedef __attribute__((address_space(3))) unsigned int lds_u32;
typedef __attribute__((address_space(1))) unsigned int glb_u32;

__device__ __forceinline__ void gload16(const void* g, void* l) {
    __builtin_amdgcn_global_load_lds((const glb_u32*)g, (lds_u32*)l, 16, 0, 0);
}

// Kernel 1: prototypes f32 -> bf16 in MFMA B-fragment order + ysq2 = ||y||^2*log2e^2.
// Element e of class c, dim d (d = kk*32 + lg*8 + e) -> bf16 offset
// ((c>>4)*4 + kk)*64*8 + (lg*16 + (c&15))*8 + e.  Tile ct occupies 4096 B.
__global__ void dce_prep(const float* __restrict__ protos,
                         unsigned short* __restrict__ bpf,
                         float* __restrict__ ysq2) {
    int c = blockIdx.x;
    int lane = threadIdx.x;  // dims 2*lane, 2*lane+1
    float2 f = ((const float2*)(protos))[c * 64 + lane];
    int d0 = lane * 2;
    int kk = d0 >> 5, sub = d0 & 31, lg = sub >> 3, e = sub & 7;
    size_t o = (((size_t)((c >> 4) * 4 + kk) * 64) + lg * 16 + (c & 15)) * 8 + e;
    bf16x2 h;
    h.x = (__bf16)f.x;
    h.y = (__bf16)f.y;
    *(bf16x2*)(bpf + o) = h;
    float xs = f.x * f.x + f.y * f.y;
#pragma unroll
    for (int d = 1; d < 64; d <<= 1) xs += __shfl_xor(xs, d);
    if (lane == 0) ysq2[c] = xs * K2f;
}

// Kernel 2: fused distance-softmax-NLL, counted-vmcnt software pipeline.
// 2048 blocks x 256 threads; block owns 128 rows, wave owns 32 rows (2 M-frags).
// B tiles staged via global_load_lds into 3 LDS buffers, prefetch depth 2;
// per-tile sync = s_waitcnt vmcnt(1) + raw s_barrier (never drains to 0).
// logits <= 0 -> softmax max pinned at 0:
//   nll = dist_label + ln2 * log2( sum_c 2^(-log2e * dist_c) ).
__global__ __launch_bounds__(256, 4) void dce_main(
    const float* __restrict__ feats,
    const float* __restrict__ protos,
    const unsigned short* __restrict__ bpf,
    const float* __restrict__ ysq2,
    const int* __restrict__ labels,
    float* __restrict__ partials, int C) {
    const int tid = threadIdx.x;
    const int lane = tid & 63;
    const int w = tid >> 6;
    const int row0 = blockIdx.x * 128;
    const int rbase = row0 + w * 32;
    const int lr = lane & 15;
    const int lg = lane >> 4;

    __shared__ __align__(16) unsigned char bsm[3][4096];
    __shared__ __align__(16) float ysql[1024];
    __shared__ float red[4];

    // ---- Issue all staging DMA first so it flies under the prologue ----
    const char* bpc = (const char*)bpf;
    gload16((const char*)ysq2 + tid * 16, (char*)ysql + tid * 16);  // 4 KB = C floats
    gload16(bpc + tid * 16, &bsm[0][tid * 16]);                     // tile 0
    gload16(bpc + 4096 + tid * 16, &bsm[1][tid * 16]);              // tile 1

    // ---- Phase 1: exact f32 label distance, 2 threads per row ----
    const int r1 = row0 + (tid >> 1);
    const int half = tid & 1;
    const int lab = labels[r1];
    const float4* fx = (const float4*)feats + (size_t)r1 * 32 + half * 16;
    const float4* px = (const float4*)protos + (size_t)lab * 32 + half * 16;
    float xx = 0.f, yy = 0.f, xy = 0.f;
#pragma unroll
    for (int i = 0; i < 16; ++i) {
        float4 f = fx[i], p = px[i];
        xx = fmaf(f.x, f.x, fmaf(f.y, f.y, fmaf(f.z, f.z, fmaf(f.w, f.w, xx))));
        yy = fmaf(p.x, p.x, fmaf(p.y, p.y, fmaf(p.z, p.z, fmaf(p.w, p.w, yy))));
        xy = fmaf(f.x, p.x, fmaf(f.y, p.y, fmaf(f.z, p.z, fmaf(f.w, p.w, xy))));
    }
    xx += __shfl_xor(xx, 1);
    yy += __shfl_xor(yy, 1);
    xy += __shfl_xor(xy, 1);
    const float ld = __builtin_amdgcn_sqrtf(fmaxf(fmaf(-2.f, xy, xx + yy), 0.f));

    // ---- A fragments: 2 M-frags x 4 k-slices ----
    bf16x8 a[2][4];
    const float4* f4 = (const float4*)feats;
#pragma unroll
    for (int m = 0; m < 2; ++m) {
        size_t r = (size_t)(rbase + m * 16 + lr);
#pragma unroll
        for (int kk = 0; kk < 4; ++kk) {
            size_t idx = r * 32 + kk * 8 + lg * 2;
            float4 lo = f4[idx];
            float4 hi = f4[idx + 1];
            bf16x8 v;
            v[0] = (__bf16)lo.x; v[1] = (__bf16)lo.y; v[2] = (__bf16)lo.z; v[3] = (__bf16)lo.w;
            v[4] = (__bf16)hi.x; v[5] = (__bf16)hi.y; v[6] = (__bf16)hi.z; v[7] = (__bf16)hi.w;
            a[m][kk] = v;
        }
    }

    // ||x||^2 (scaled) in C/D layout: element (m,reg) covers row m*16+lg*4+reg,
    // whose exact xx lives at lane 2*(that row-in-wave).
    float xsqs[2][4];
#pragma unroll
    for (int m = 0; m < 2; ++m)
#pragma unroll
        for (int reg = 0; reg < 4; ++reg)
            xsqs[m][reg] = K2f * __shfl(xx, 2 * (m * 16 + lg * 4 + reg));

    float lacc[2][4];
#pragma unroll
    for (int m = 0; m < 2; ++m)
#pragma unroll
        for (int reg = 0; reg < 4; ++reg) lacc[m][reg] = 0.f;

    // ---- Prologue drain: ysql + tiles 0,1 resident; from here on the only
    //      in-flight VMEM ops are stage DMAs, so vmcnt counting is exact. ----
    asm volatile("s_waitcnt vmcnt(0)" ::: "memory");
    __builtin_amdgcn_s_barrier();

    const int nt = C >> 4;  // 64
    int rb = 0;             // buffer holding tile t
    for (int t = 0; t < nt; ++t) {
        // stage tile t+2 into the buffer read at iter t-1 ((t+2) % 3 == (t-1) % 3)
        int sb = rb - 1;
        if (sb < 0) sb = 2;
        if (t + 2 < nt)
            gload16(bpc + (size_t)(t + 2) * 4096 + tid * 16, &bsm[sb][tid * 16]);

        const bf16x8* bl = (const bf16x8*)&bsm[rb][0];
        bf16x8 b0 = bl[lane];
        bf16x8 b1 = bl[64 + lane];
        bf16x8 b2 = bl[128 + lane];
        bf16x8 b3 = bl[192 + lane];
        const float yq2 = ysql[t * 16 + lr];
#pragma unroll
        for (int m = 0; m < 2; ++m) {
            f32x4 acc = {0.f, 0.f, 0.f, 0.f};
            acc = __builtin_amdgcn_mfma_f32_16x16x32_bf16(a[m][0], b0, acc, 0, 0, 0);
            acc = __builtin_amdgcn_mfma_f32_16x16x32_bf16(a[m][1], b1, acc, 0, 0, 0);
            acc = __builtin_amdgcn_mfma_f32_16x16x32_bf16(a[m][2], b2, acc, 0, 0, 0);
            acc = __builtin_amdgcn_mfma_f32_16x16x32_bf16(a[m][3], b3, acc, 0, 0, 0);
#pragma unroll
            for (int reg = 0; reg < 4; ++reg) {
                float d = fmaf(-2.f * K2f, acc[reg], xsqs[m][reg] + yq2);
                d = fmaxf(d, 0.f);
                float s = __builtin_amdgcn_sqrtf(d);      // = log2e * dist
                lacc[m][reg] += __builtin_amdgcn_exp2f(-s);
            }
        }

        // Wait stage(t+1) only; stage(t+2) stays in flight across the barrier.
        asm volatile("s_waitcnt vmcnt(1)" ::: "memory");
        __builtin_amdgcn_s_barrier();
        rb = rb + 1;
        if (rb == 3) rb = 0;
    }

    // ---- Reduce over 16 column-lanes per row, add exact label distance ----
    float ssum = 0.f;
#pragma unroll
    for (int m = 0; m < 2; ++m)
#pragma unroll
        for (int reg = 0; reg < 4; ++reg) {
            float l = lacc[m][reg];
            l += __shfl_xor(l, 1);
            l += __shfl_xor(l, 2);
            l += __shfl_xor(l, 4);
            l += __shfl_xor(l, 8);
            float ldv = __shfl(ld, 2 * (m * 16 + lg * 4 + reg));
            if (lr == 0) ssum += ldv + LN2f * __builtin_amdgcn_logf(l);
        }
    ssum += __shfl_xor(ssum, 16);
    ssum += __shfl_xor(ssum, 32);

    if (lane == 0) red[w] = ssum;
    __syncthreads();
    if (tid == 0) partials[blockIdx.x] = red[0] + red[1] + red[2] + red[3];
}

// Kernel 3: deterministic reduction of per-block partials -> mean.
__global__ void dce_finish(const float* __restrict__ partials,
                           float* __restrict__ out, int nblocks, float invN) {
    int tid = threadIdx.x;  // 256
    float s = 0.f;
    for (int i = tid; i < nblocks; i += 256) s += partials[i];
#pragma unroll
    for (int d = 1; d < 64; d <<= 1) s += __shfl_xor(s, d);
    __shared__ float red[4];
    if ((tid & 63) == 0) red[tid >> 6] = s;
    __syncthreads();
    if (tid == 0) out[0] = (red[0] + red[1] + red[2] + red[3]) * invN;
}

extern "C" void kernel_launch(void* const* d_in, const int* in_sizes, int n_in,
                              void* d_out, int out_size, void* d_ws, size_t ws_size,
                              hipStream_t stream) {
    const float* feats = (const float*)d_in[0];
    const float* protos = (const float*)d_in[1];
    const int* labels = (const int*)d_in[2];
    const int N = in_sizes[2];          // 262144
    const int C = in_sizes[1] / 128;    // 1024
    float* out = (float*)d_out;

    // Workspace: [bpf: C*128*2B][ysq2: C*4B][partials: N/128*4B]
    unsigned short* bpf = (unsigned short*)d_ws;
    float* ysq2 = (float*)((char*)d_ws + (size_t)C * 128 * 2);
    float* partials = ysq2 + C;
    const int nblocks = N / 128;

    dce_prep<<<C, 64, 0, stream>>>(protos, bpf, ysq2);
    dce_main<<<nblocks, 256, 0, stream>>>(feats, protos, bpf, ysq2, labels, partials, C);
    dce_finish<<<1, 256, 0, stream>>>(partials, out, nblocks, 1.0f / (float)N);
}